// Round 1
// baseline (990.849 us; speedup 1.0000x reference)
//
#include <hip/hip_runtime.h>
#include <math.h>

#define IMG_H 256
#define IMG_W 256
#define NBATCH 32
#define TILE 16
#define NC 16     // n convs / channels
#define NP 9      // in_features (3x3 patch)
#define NG 8      // spline coeffs per input

// grid[i] = (i-3) * (2/5) - 1, computed in fp32 exactly like the jnp reference
__device__ __forceinline__ constexpr float gridv(int i) {
    return (float)(i - 3) * (float)(2.0 / 5.0) - 1.0f;
}

__global__ __launch_bounds__(256) void kkan_fused(
    const float* __restrict__ x,
    const float* __restrict__ base_w,
    const float* __restrict__ spline_w,
    const float* __restrict__ spline_scaler,
    const float* __restrict__ restore_w,
    const float* __restrict__ restore_b,
    float* __restrict__ out)
{
    __shared__ float s_bw[NC * NP];          // base_w [c][p]
    __shared__ float s_ssw[NC * NP * NG];    // spline_w * scaler [c][p][g]
    __shared__ float s_rw[NC * 9];           // restore conv weights [c][ky*3+kx]
    __shared__ float s_x[20 * 20];           // x tile with 2-halo
    __shared__ float s_feat[NC][18][19];     // feat tile with 1-halo, padded stride

    const int tid = threadIdx.x;
    const int gx0 = blockIdx.x * TILE;
    const int gy0 = blockIdx.y * TILE;
    const int b   = blockIdx.z;

    // ---- stage weights ----
    if (tid < NC * NP) s_bw[tid] = base_w[tid];
    for (int i = tid; i < NC * NP * NG; i += 256)
        s_ssw[i] = spline_w[i] * spline_scaler[i / NG];
    if (tid < NC * 9) s_rw[tid] = restore_w[tid];

    // ---- stage x tile (zero-padded outside image) ----
    const float* xb = x + (size_t)b * IMG_H * IMG_W;
    for (int i = tid; i < 400; i += 256) {
        int r = i / 20, c = i % 20;
        int gy = gy0 - 2 + r, gx = gx0 - 2 + c;
        float v = 0.0f;
        if (gy >= 0 && gy < IMG_H && gx >= 0 && gx < IMG_W)
            v = xb[gy * IMG_W + gx];
        s_x[i] = v;
    }
    __syncthreads();

    // ---- compute feat tile: 18x18 positions x 16 channels ----
    for (int pos = tid; pos < 18 * 18; pos += 256) {
        const int fy = pos / 18, fx = pos % 18;
        const int gy = gy0 - 1 + fy, gx = gx0 - 1 + fx;
        float acc[NC];
        #pragma unroll
        for (int c = 0; c < NC; ++c) acc[c] = 0.0f;

        if (gy >= 0 && gy < IMG_H && gx >= 0 && gx < IMG_W) {
            #pragma unroll
            for (int p = 0; p < NP; ++p) {
                const int di = p / 3, dj = p % 3;
                const float v = s_x[(fy + di) * 20 + (fx + dj)];

                // SiLU
                const float sil = v / (1.0f + __expf(-v));

                // Cox-de Boor cubic B-spline bases (11 -> 10 -> 9 -> 8)
                float t[11];
                #pragma unroll
                for (int i = 0; i < 11; ++i)
                    t[i] = (v >= gridv(i) && v < gridv(i + 1)) ? 1.0f : 0.0f;
                #pragma unroll
                for (int k = 1; k <= 3; ++k) {
                    #pragma unroll
                    for (int i = 0; i + k < 11; ++i) {
                        const float lc = (v - gridv(i)) *
                                         (1.0f / (gridv(i + k) - gridv(i)));
                        const float rc = (gridv(i + k + 1) - v) *
                                         (1.0f / (gridv(i + k + 1) - gridv(i + 1)));
                        t[i] = lc * t[i] + rc * t[i + 1];
                    }
                }

                // accumulate into 16 channels
                #pragma unroll
                for (int c = 0; c < NC; ++c) {
                    float a = sil * s_bw[c * NP + p];
                    const float* w = &s_ssw[(c * NP + p) * NG];
                    #pragma unroll
                    for (int g = 0; g < NG; ++g) a = fmaf(t[g], w[g], a);
                    acc[c] += a;
                }
            }
        }
        #pragma unroll
        for (int c = 0; c < NC; ++c) s_feat[c][fy][fx] = acc[c];
    }
    __syncthreads();

    // ---- restore conv 16->1, 3x3, + bias ----
    const int ty = tid / 16, tx = tid % 16;
    float o = restore_b[0];
    #pragma unroll
    for (int c = 0; c < NC; ++c) {
        #pragma unroll
        for (int dy = 0; dy < 3; ++dy) {
            #pragma unroll
            for (int dx = 0; dx < 3; ++dx) {
                o = fmaf(s_feat[c][ty + dy][tx + dx], s_rw[c * 9 + dy * 3 + dx], o);
            }
        }
    }
    out[(size_t)b * IMG_H * IMG_W + (gy0 + ty) * IMG_W + (gx0 + tx)] = o;
}

extern "C" void kernel_launch(void* const* d_in, const int* in_sizes, int n_in,
                              void* d_out, int out_size, void* d_ws, size_t ws_size,
                              hipStream_t stream) {
    const float* x            = (const float*)d_in[0];
    const float* base_w       = (const float*)d_in[1];
    const float* spline_w     = (const float*)d_in[2];
    const float* spline_scaler= (const float*)d_in[3];
    const float* restore_w    = (const float*)d_in[4];
    const float* restore_b    = (const float*)d_in[5];
    float* out = (float*)d_out;

    dim3 grid(IMG_W / TILE, IMG_H / TILE, NBATCH);
    dim3 block(256);
    kkan_fused<<<grid, block, 0, stream>>>(x, base_w, spline_w, spline_scaler,
                                           restore_w, restore_b, out);
}

// Round 2
// 104.409 us; speedup vs baseline: 9.4901x; 9.4901x over previous
//
#include <hip/hip_runtime.h>
#include <math.h>

#define IMG 256
#define NC 16
#define NP 9
#define NG 8
#define TS 32   // output tile side

// grid[i] = (i-3) * (2/5) - 1, fp32, identical to the jnp reference
__device__ __forceinline__ constexpr float gridv(int i) {
    return (float)(i - 3) * 0.4f - 1.0f;
}

// ---------------------------------------------------------------------------
// Precompute kernel: F[u][p][j] and packed E[j][sy][8] into d_ws.
//   F[u][p][j] = sum_c restore_w[c,u] * W[c,p,j]
//     W[c,p,j] = (j<8) ? spline_w[c,p,j]*scaler[c,p] : base_w[c,p]
//   E[(sy,sx)][j] = sum_{u+p=s} F[u][p][j]   (composition of the two 3x3 convs)
// ws layout (floats): [0..359] E packed [j][sy][8] (sx in 0..4), [360..1088] F
// ---------------------------------------------------------------------------
__global__ __launch_bounds__(1024) void kkan_precompute(
    const float* __restrict__ bw, const float* __restrict__ sw,
    const float* __restrict__ sc, const float* __restrict__ rw,
    float* __restrict__ ws)
{
    __shared__ float sF[729];
    const int tid = threadIdx.x;
    if (tid < 729) {
        const int u = tid / 81, p = (tid / 9) % 9, j = tid % 9;
        float f = 0.f;
        for (int c = 0; c < NC; ++c) {
            const float w = (j < 8) ? sw[(c * NP + p) * NG + j] * sc[c * NP + p]
                                    : bw[c * NP + p];
            f += rw[c * NP + u] * w;
        }
        sF[tid] = f;
        ws[360 + tid] = f;
    }
    __syncthreads();
    if (tid < 225) {
        const int j = tid / 25, sy = (tid % 25) / 5, sx = tid % 5;
        float e = 0.f;
        for (int uy = 0; uy < 3; ++uy) {
            const int py = sy - uy;
            if (py < 0 || py > 2) continue;
            for (int ux = 0; ux < 3; ++ux) {
                const int px = sx - ux;
                if (px < 0 || px > 2) continue;
                e += sF[((uy * 3 + ux) * 9 + (py * 3 + px)) * 9 + j];
            }
        }
        ws[(j * 5 + sy) * 8 + sx] = e;
    }
}

// ---------------------------------------------------------------------------
// Main fused kernel: phi (8 bases + silu per pixel) -> 5x5x9 conv with E,
// border-masked via F corrections.
// ---------------------------------------------------------------------------
__global__ __launch_bounds__(256) void kkan_main(
    const float* __restrict__ x, const float* __restrict__ ws,
    const float* __restrict__ rb, float* __restrict__ out)
{
    __shared__ __align__(16) float s_phi[9][36][40];  // SoA, padded stride
    __shared__ __align__(16) float s_E[360];
    __shared__ float s_F[729];

    const int tid = threadIdx.x;
    const int gx0 = blockIdx.x * TS, gy0 = blockIdx.y * TS, b = blockIdx.z;

    for (int i = tid; i < 1089; i += 256) {
        const float v = ws[i];
        if (i < 360) s_E[i] = v; else s_F[i - 360] = v;
    }

    const float* xb = x + (size_t)b * (IMG * IMG);

    // ---- phi over the 36x36 pixel halo (zero-padded x outside image) ----
    for (int pix = tid; pix < 36 * 36; pix += 256) {
        const int yy = pix / 36, xx = pix % 36;
        const int gy = gy0 - 2 + yy, gx = gx0 - 2 + xx;
        float v = 0.f;
        if ((unsigned)gy < (unsigned)IMG && (unsigned)gx < (unsigned)IMG)
            v = xb[gy * IMG + gx];

        const float sil = v / (1.f + __expf(-v));

        float t[11];
        #pragma unroll
        for (int i = 0; i < 11; ++i)
            t[i] = (v >= gridv(i) && v < gridv(i + 1)) ? 1.f : 0.f;
        #pragma unroll
        for (int k = 1; k <= 3; ++k) {
            #pragma unroll
            for (int i = 0; i + k < 11; ++i) {
                const float lc = (v - gridv(i)) * (1.f / (gridv(i + k) - gridv(i)));
                const float rc = (gridv(i + k + 1) - v) *
                                 (1.f / (gridv(i + k + 1) - gridv(i + 1)));
                t[i] = lc * t[i] + rc * t[i + 1];
            }
        }
        #pragma unroll
        for (int j = 0; j < 8; ++j) s_phi[j][yy][xx] = t[j];
        s_phi[8][yy][xx] = sil;
    }
    __syncthreads();

    // ---- fast path: each thread owns 4 consecutive x pixels ----
    const int ly = tid / 8;            // 0..31
    const int lx0 = (tid % 8) * 4;     // 0,4,...,28
    float acc0 = 0.f, acc1 = 0.f, acc2 = 0.f, acc3 = 0.f;

    #pragma unroll
    for (int j = 0; j < 9; ++j) {
        #pragma unroll
        for (int sy = 0; sy < 5; ++sy) {
            const float4 a  = *(const float4*)&s_phi[j][ly + sy][lx0];
            const float4 bq = *(const float4*)&s_phi[j][ly + sy][lx0 + 4];
            const float4 e  = *(const float4*)&s_E[(j * 5 + sy) * 8];
            const float  e4 = s_E[(j * 5 + sy) * 8 + 4];
            acc0 = fmaf(e.x, a.x, fmaf(e.y, a.y, fmaf(e.z, a.z, fmaf(e.w, a.w, fmaf(e4, bq.x, acc0)))));
            acc1 = fmaf(e.x, a.y, fmaf(e.y, a.z, fmaf(e.z, a.w, fmaf(e.w, bq.x, fmaf(e4, bq.y, acc1)))));
            acc2 = fmaf(e.x, a.z, fmaf(e.y, a.w, fmaf(e.z, bq.x, fmaf(e.w, bq.y, fmaf(e4, bq.z, acc2)))));
            acc3 = fmaf(e.x, a.w, fmaf(e.y, bq.x, fmaf(e.z, bq.y, fmaf(e.w, bq.z, fmaf(e4, bq.w, acc3)))));
        }
    }

    // ---- border correction: subtract contributions of masked feat positions.
    // feat position q = o + u - 1 outside the image must contribute 0, but the
    // E-path added sum_{p,j} F[u][p][j] * phi_j(q+p-1). Subtract it back.
    const int gy  = gy0 + ly;
    const int gxb = gx0 + lx0;
    if (gy < 2 || gy > 253 || gxb < 2 || gxb > 250) {
        #pragma unroll
        for (int i = 0; i < 4; ++i) {
            const int gx = gxb + i;
            float corr = 0.f;
            for (int uy = 0; uy < 3; ++uy) {
                const int qy = gy + uy - 1;
                for (int ux = 0; ux < 3; ++ux) {
                    const int qx = gx + ux - 1;
                    if ((unsigned)qy < (unsigned)IMG && (unsigned)qx < (unsigned)IMG)
                        continue;  // inside -> no mask -> no correction
                    for (int p = 0; p < 9; ++p) {
                        const int ry = ly + uy + (p / 3);
                        const int rx = lx0 + i + ux + (p % 3);
                        const float* fp = &s_F[((uy * 3 + ux) * 9 + p) * 9];
                        for (int j = 0; j < 9; ++j)
                            corr += fp[j] * s_phi[j][ry][rx];
                    }
                }
            }
            if (i == 0) acc0 -= corr;
            else if (i == 1) acc1 -= corr;
            else if (i == 2) acc2 -= corr;
            else acc3 -= corr;
        }
    }

    const float rbv = rb[0];
    float4 o4;
    o4.x = acc0 + rbv; o4.y = acc1 + rbv; o4.z = acc2 + rbv; o4.w = acc3 + rbv;
    *(float4*)&out[(size_t)b * (IMG * IMG) + gy * IMG + gxb] = o4;
}

extern "C" void kernel_launch(void* const* d_in, const int* in_sizes, int n_in,
                              void* d_out, int out_size, void* d_ws, size_t ws_size,
                              hipStream_t stream) {
    const float* x             = (const float*)d_in[0];
    const float* base_w        = (const float*)d_in[1];
    const float* spline_w      = (const float*)d_in[2];
    const float* spline_scaler = (const float*)d_in[3];
    const float* restore_w     = (const float*)d_in[4];
    const float* restore_b     = (const float*)d_in[5];
    float* out = (float*)d_out;
    float* ws  = (float*)d_ws;

    kkan_precompute<<<dim3(1), dim3(1024), 0, stream>>>(
        base_w, spline_w, spline_scaler, restore_w, ws);

    dim3 grid(IMG / TS, IMG / TS, 32);
    kkan_main<<<grid, dim3(256), 0, stream>>>(x, ws, restore_b, out);
}

// Round 3
// 62.578 us; speedup vs baseline: 15.8338x; 1.6684x over previous
//
#include <hip/hip_runtime.h>
#include <math.h>

#define IMG 256
#define TS 32

typedef _Float16 half_t;
typedef _Float16 half2_t __attribute__((ext_vector_type(2)));

__device__ __forceinline__ half2_t bc_h2(unsigned int u) {
    union { unsigned int u; half2_t h; } c; c.u = u; return c.h;
}
__device__ __forceinline__ unsigned int bc_u(half2_t h) {
    union { unsigned int u; half2_t h; } c; c.h = h; return c.u;
}

__device__ __forceinline__ float dot2(half2_t a, half2_t b, float c) {
#if __has_builtin(__builtin_amdgcn_fdot2)
    return __builtin_amdgcn_fdot2(a, b, c, false);
#else
    return fmaf((float)a.x, (float)b.x, fmaf((float)a.y, (float)b.y, c));
#endif
}

// ws layout (32-bit slots): [0..728] F fp32 ; [736..1023] E half2 (uint) [j][32]
//   per j: slots sy*6 + {0,1,2}=even-phase pairs (e0,e1)(e2,e3)(e4,0),
//                  {3,4,5}=odd-phase pairs (0,e0)(e1,e2)(e3,e4); 30,31 pad.
__global__ __launch_bounds__(1024) void kkan_precompute(
    const float* __restrict__ bw, const float* __restrict__ sw,
    const float* __restrict__ sc, const float* __restrict__ rw,
    float* __restrict__ ws)
{
    __shared__ float sF[729];
    const int tid = threadIdx.x;
    if (tid < 729) {
        const int u = tid / 81, p = (tid / 9) % 9, j = tid % 9;
        float f = 0.f;
        for (int c = 0; c < 16; ++c) {
            const float w = (j < 8) ? sw[(c * 9 + p) * 8 + j] * sc[c * 9 + p]
                                    : bw[c * 9 + p];
            f += rw[c * 9 + u] * w;
        }
        sF[tid] = f;
        ws[tid] = f;
    }
    __syncthreads();
    unsigned int* wse = (unsigned int*)ws + 736;
    if (tid < 9) { wse[tid * 32 + 30] = 0; wse[tid * 32 + 31] = 0; }
    if (tid < 45) {
        const int j = tid / 5, sy = tid % 5;
        float e[5];
        for (int sx = 0; sx < 5; ++sx) {
            float acc = 0.f;
            for (int uy = 0; uy < 3; ++uy) {
                const int py = sy - uy;
                if (py < 0 || py > 2) continue;
                for (int ux = 0; ux < 3; ++ux) {
                    const int px = sx - ux;
                    if (px < 0 || px > 2) continue;
                    acc += sF[((uy * 3 + ux) * 9 + (py * 3 + px)) * 9 + j];
                }
            }
            e[sx] = acc;
        }
        unsigned int* o = wse + j * 32 + sy * 6;
        o[0] = bc_u(half2_t{(half_t)e[0], (half_t)e[1]});
        o[1] = bc_u(half2_t{(half_t)e[2], (half_t)e[3]});
        o[2] = bc_u(half2_t{(half_t)e[4], (half_t)0.f});
        o[3] = bc_u(half2_t{(half_t)0.f, (half_t)e[0]});
        o[4] = bc_u(half2_t{(half_t)e[1], (half_t)e[2]});
        o[5] = bc_u(half2_t{(half_t)e[3], (half_t)e[4]});
    }
}

__global__ __launch_bounds__(256) void kkan_main(
    const float* __restrict__ x, const float* __restrict__ ws,
    const float* __restrict__ rb, float* __restrict__ out)
{
    __shared__ __align__(16) half_t s_phi[9][36][40];   // 25.9 KB, SoA
    __shared__ __align__(16) unsigned int s_e[288];     // 1.2 KB
    __shared__ float s_F[729];                          // 2.9 KB

    const int tid = threadIdx.x;
    const int gx0 = blockIdx.x * TS, gy0 = blockIdx.y * TS, b = blockIdx.z;

    const unsigned int* wsu = (const unsigned int*)ws;
    for (int i = tid; i < 288; i += 256) s_e[i] = wsu[736 + i];
    for (int i = tid; i < 729; i += 256) s_F[i] = ws[i];

    const float* xb = x + (size_t)b * (IMG * IMG);

    // ---- phi over the 36x36 halo: closed-form uniform cubic B-spline ----
    for (int pix = tid; pix < 36 * 36; pix += 256) {
        const int yy = pix / 36, xx = pix % 36;
        const int gy = gy0 - 2 + yy, gx = gx0 - 2 + xx;
        float v = 0.f;
        if ((unsigned)gy < (unsigned)IMG && (unsigned)gx < (unsigned)IMG)
            v = xb[gy * IMG + gx];

        const float sil = v / (1.f + __expf(-v));

        #pragma unroll
        for (int j = 0; j < 8; ++j) s_phi[j][yy][xx] = (half_t)0.f;

        const int cell = (int)floorf((v + 2.2f) * 2.5f);
        if (cell >= 0 && cell <= 10) {
            const float g0 = (float)(cell - 3) * 0.4f - 1.0f;
            const float u = (v - g0) * 2.5f;
            const float um = 1.f - u, u2 = u * u, u3 = u2 * u;
            const float w0 = um * um * um * (1.f / 6.f);
            const float w1 = (3.f * u3 - 6.f * u2 + 4.f) * (1.f / 6.f);
            const float w2 = (-3.f * u3 + 3.f * u2 + 3.f * u + 1.f) * (1.f / 6.f);
            const float w3 = u3 * (1.f / 6.f);
            const int j0 = cell - 3;
            if (j0 >= 0 && j0 < 8)     s_phi[j0][yy][xx]     = (half_t)w0;
            if (j0 + 1 >= 0 && j0 + 1 < 8) s_phi[j0 + 1][yy][xx] = (half_t)w1;
            if (j0 + 2 >= 0 && j0 + 2 < 8) s_phi[j0 + 2][yy][xx] = (half_t)w2;
            if (j0 + 3 >= 0 && j0 + 3 < 8) s_phi[j0 + 3][yy][xx] = (half_t)w3;
        }
        s_phi[8][yy][xx] = (half_t)sil;
    }
    __syncthreads();

    // ---- 5x5x9 conv: each thread owns 4 consecutive x pixels ----
    const int ly = tid >> 3;
    const int lx0 = (tid & 7) * 4;
    float a0 = 0.f, a1 = 0.f, a2 = 0.f, a3 = 0.f;

    #pragma unroll
    for (int j = 0; j < 9; ++j) {
        #pragma unroll
        for (int sy = 0; sy < 5; ++sy) {
            const uint2* eb = (const uint2*)&s_e[j * 32 + sy * 6];
            const uint2 q0 = eb[0], q1 = eb[1], q2 = eb[2];
            const half2_t ev0 = bc_h2(q0.x), ev1 = bc_h2(q0.y), ev2 = bc_h2(q1.x);
            const half2_t od0 = bc_h2(q1.y), od1 = bc_h2(q2.x), od2 = bc_h2(q2.y);
            const uint2* pp = (const uint2*)&s_phi[j][ly + sy][lx0];
            const uint2 ph0 = pp[0], ph1 = pp[1];
            const half2_t P0 = bc_h2(ph0.x), P1 = bc_h2(ph0.y);
            const half2_t P2 = bc_h2(ph1.x), P3 = bc_h2(ph1.y);
            a0 = dot2(P0, ev0, dot2(P1, ev1, dot2(P2, ev2, a0)));
            a1 = dot2(P0, od0, dot2(P1, od1, dot2(P2, od2, a1)));
            a2 = dot2(P1, ev0, dot2(P2, ev1, dot2(P3, ev2, a2)));
            a3 = dot2(P1, od0, dot2(P2, od1, dot2(P3, od2, a3)));
        }
    }

    // ---- border correction (rare): subtract masked feat contributions ----
    const int gy  = gy0 + ly;
    const int gxb = gx0 + lx0;
    if (gy < 2 || gy > 253 || gxb < 2 || gxb > 250) {
        #pragma unroll
        for (int i = 0; i < 4; ++i) {
            const int gx = gxb + i;
            float corr = 0.f;
            for (int uy = 0; uy < 3; ++uy) {
                const int qy = gy + uy - 1;
                for (int ux = 0; ux < 3; ++ux) {
                    const int qx = gx + ux - 1;
                    if ((unsigned)qy < (unsigned)IMG && (unsigned)qx < (unsigned)IMG)
                        continue;
                    for (int p = 0; p < 9; ++p) {
                        const int ry = ly + uy + (p / 3);
                        const int rx = lx0 + i + ux + (p % 3);
                        const float* fp = &s_F[((uy * 3 + ux) * 9 + p) * 9];
                        for (int jj = 0; jj < 9; ++jj)
                            corr += fp[jj] * (float)s_phi[jj][ry][rx];
                    }
                }
            }
            if (i == 0) a0 -= corr;
            else if (i == 1) a1 -= corr;
            else if (i == 2) a2 -= corr;
            else a3 -= corr;
        }
    }

    const float rbv = rb[0];
    float4 o4; o4.x = a0 + rbv; o4.y = a1 + rbv; o4.z = a2 + rbv; o4.w = a3 + rbv;
    *(float4*)&out[(size_t)b * (IMG * IMG) + gy * IMG + gxb] = o4;
}

extern "C" void kernel_launch(void* const* d_in, const int* in_sizes, int n_in,
                              void* d_out, int out_size, void* d_ws, size_t ws_size,
                              hipStream_t stream) {
    const float* x             = (const float*)d_in[0];
    const float* base_w        = (const float*)d_in[1];
    const float* spline_w      = (const float*)d_in[2];
    const float* spline_scaler = (const float*)d_in[3];
    const float* restore_w     = (const float*)d_in[4];
    const float* restore_b     = (const float*)d_in[5];
    float* out = (float*)d_out;
    float* ws  = (float*)d_ws;

    kkan_precompute<<<dim3(1), dim3(1024), 0, stream>>>(
        base_w, spline_w, spline_scaler, restore_w, ws);

    dim3 grid(IMG / TS, IMG / TS, 32);
    kkan_main<<<grid, dim3(256), 0, stream>>>(x, ws, restore_b, out);
}

// Round 4
// 45.535 us; speedup vs baseline: 21.7603x; 1.3743x over previous
//
#include <hip/hip_runtime.h>
#include <math.h>

#define IMG 256
#define TS 32
#define EBASE 736   // uint slot offset of packed E in ws

typedef _Float16 half_t;
typedef _Float16 half2_t __attribute__((ext_vector_type(2)));

__device__ __forceinline__ half2_t bc_h2(unsigned int u) {
    union { unsigned int u; half2_t h; } c; c.u = u; return c.h;
}
__device__ __forceinline__ unsigned int bc_u(half2_t h) {
    union { unsigned int u; half2_t h; } c; c.h = h; return c.u;
}

__device__ __forceinline__ float dot2(half2_t a, half2_t b, float c) {
#if __has_builtin(__builtin_amdgcn_fdot2)
    return __builtin_amdgcn_fdot2(a, b, c, false);
#else
    return fmaf((float)a.x, (float)b.x, fmaf((float)a.y, (float)b.y, c));
#endif
}

// ws layout (32-bit slots):
//   [0..728]           F fp32  (F[u][p][j], border corrections read this)
//   [EBASE..EBASE+287] E packed per j: 32 uints = 16 "even" + 16 "odd"
//     ev slot j*32 + sy*3 + k     : pairs (e0,e1)(e2,e3)(e4,0)
//     od slot j*32 + 16 + sy*3 + k: pairs (0,e0)(e1,e2)(e3,e4)
__global__ __launch_bounds__(1024) void kkan_precompute(
    const float* __restrict__ bw, const float* __restrict__ sw,
    const float* __restrict__ sc, const float* __restrict__ rw,
    float* __restrict__ ws)
{
    __shared__ float sF[729];
    const int tid = threadIdx.x;
    unsigned int* wse = (unsigned int*)ws + EBASE;
    if (tid < 729) {
        const int u = tid / 81, p = (tid / 9) % 9, j = tid % 9;
        float f = 0.f;
        for (int c = 0; c < 16; ++c) {
            const float w = (j < 8) ? sw[(c * 9 + p) * 8 + j] * sc[c * 9 + p]
                                    : bw[c * 9 + p];
            f += rw[c * 9 + u] * w;
        }
        sF[tid] = f;
        ws[tid] = f;
    } else if (tid < 729 + 288) {
        wse[tid - 729] = 0u;
    }
    __syncthreads();
    if (tid < 45) {
        const int j = tid / 5, sy = tid % 5;
        float e[5];
        for (int sx = 0; sx < 5; ++sx) {
            float acc = 0.f;
            for (int uy = 0; uy < 3; ++uy) {
                const int py = sy - uy;
                if (py < 0 || py > 2) continue;
                for (int ux = 0; ux < 3; ++ux) {
                    const int px = sx - ux;
                    if (px < 0 || px > 2) continue;
                    acc += sF[((uy * 3 + ux) * 9 + (py * 3 + px)) * 9 + j];
                }
            }
            e[sx] = acc;
        }
        unsigned int* oe = wse + j * 32 + sy * 3;
        oe[0] = bc_u(half2_t{(half_t)e[0], (half_t)e[1]});
        oe[1] = bc_u(half2_t{(half_t)e[2], (half_t)e[3]});
        oe[2] = bc_u(half2_t{(half_t)e[4], (half_t)0.f});
        unsigned int* oo = wse + j * 32 + 16 + sy * 3;
        oo[0] = bc_u(half2_t{(half_t)0.f, (half_t)e[0]});
        oo[1] = bc_u(half2_t{(half_t)e[1], (half_t)e[2]});
        oo[2] = bc_u(half2_t{(half_t)e[3], (half_t)e[4]});
    }
}

__global__ __launch_bounds__(256, 6) void kkan_main(
    const float* __restrict__ x, const float* __restrict__ ws,
    const float* __restrict__ rb, float* __restrict__ out)
{
    __shared__ __align__(16) half_t s_phi[9][36][40];   // 25.9 KB, only LDS user

    const int tid = threadIdx.x;
    const int gx0 = blockIdx.x * TS, gy0 = blockIdx.y * TS, b = blockIdx.z;

    // ---- vectorized zero-fill of phi (9*36*40*2B = 25920B = 1620 uint4) ----
    {
        uint4 z; z.x = 0u; z.y = 0u; z.z = 0u; z.w = 0u;
        uint4* p = (uint4*)s_phi;
        for (int i = tid; i < 1620; i += 256) p[i] = z;
    }
    __syncthreads();

    const float* xb = x + (size_t)b * (IMG * IMG);

    // ---- phi over the 36x36 halo: closed-form uniform cubic B-spline ----
    for (int pix = tid; pix < 36 * 36; pix += 256) {
        const int yy = pix / 36, xx = pix % 36;
        const int gy = gy0 - 2 + yy, gx = gx0 - 2 + xx;
        float v = 0.f;
        if ((unsigned)gy < (unsigned)IMG && (unsigned)gx < (unsigned)IMG)
            v = xb[gy * IMG + gx];

        const float sil = v / (1.f + __expf(-v));

        const int cell = (int)floorf((v + 2.2f) * 2.5f);
        if (cell >= 0 && cell <= 10) {
            const float g0 = (float)(cell - 3) * 0.4f - 1.0f;
            const float u = (v - g0) * 2.5f;
            const float um = 1.f - u, u2 = u * u, u3 = u2 * u;
            const float w0 = um * um * um * (1.f / 6.f);
            const float w1 = (3.f * u3 - 6.f * u2 + 4.f) * (1.f / 6.f);
            const float w2 = (-3.f * u3 + 3.f * u2 + 3.f * u + 1.f) * (1.f / 6.f);
            const float w3 = u3 * (1.f / 6.f);
            const int j0 = cell - 3;
            if (j0 >= 0 && j0 < 8)         s_phi[j0][yy][xx]     = (half_t)w0;
            if (j0 + 1 >= 0 && j0 + 1 < 8) s_phi[j0 + 1][yy][xx] = (half_t)w1;
            if (j0 + 2 >= 0 && j0 + 2 < 8) s_phi[j0 + 2][yy][xx] = (half_t)w2;
            if (j0 + 3 >= 0 && j0 + 3 < 8) s_phi[j0 + 3][yy][xx] = (half_t)w3;
        }
        s_phi[8][yy][xx] = (half_t)sil;
    }
    __syncthreads();

    // ---- 5x5x9 conv: 4 consecutive x pixels per thread, E from global ----
    const int ly = tid >> 3;
    const int lx0 = (tid & 7) * 4;

    const uint4* Eg = (const uint4*)((const unsigned int*)ws + EBASE);

    float aA0 = 0.f, aB0 = 0.f, aC0 = 0.f;
    float aA1 = 0.f, aB1 = 0.f, aC1 = 0.f;
    float aA2 = 0.f, aB2 = 0.f, aC2 = 0.f;
    float aA3 = 0.f, aB3 = 0.f, aC3 = 0.f;

    #pragma unroll
    for (int j = 0; j < 9; ++j) {
        unsigned int ej[32];
        #pragma unroll
        for (int q = 0; q < 8; ++q) {
            const uint4 t = Eg[j * 8 + q];
            ej[q * 4 + 0] = t.x; ej[q * 4 + 1] = t.y;
            ej[q * 4 + 2] = t.z; ej[q * 4 + 3] = t.w;
        }
        #pragma unroll
        for (int sy = 0; sy < 5; ++sy) {
            const half2_t ev0 = bc_h2(ej[sy * 3 + 0]);
            const half2_t ev1 = bc_h2(ej[sy * 3 + 1]);
            const half2_t ev2 = bc_h2(ej[sy * 3 + 2]);
            const half2_t od0 = bc_h2(ej[16 + sy * 3 + 0]);
            const half2_t od1 = bc_h2(ej[16 + sy * 3 + 1]);
            const half2_t od2 = bc_h2(ej[16 + sy * 3 + 2]);
            const uint2* pp = (const uint2*)&s_phi[j][ly + sy][lx0];
            const uint2 ph0 = pp[0], ph1 = pp[1];
            const half2_t P0 = bc_h2(ph0.x), P1 = bc_h2(ph0.y);
            const half2_t P2 = bc_h2(ph1.x), P3 = bc_h2(ph1.y);
            aA0 = dot2(P0, ev0, aA0); aB0 = dot2(P1, ev1, aB0); aC0 = dot2(P2, ev2, aC0);
            aA1 = dot2(P0, od0, aA1); aB1 = dot2(P1, od1, aB1); aC1 = dot2(P2, od2, aC1);
            aA2 = dot2(P1, ev0, aA2); aB2 = dot2(P2, ev1, aB2); aC2 = dot2(P3, ev2, aC2);
            aA3 = dot2(P1, od0, aA3); aB3 = dot2(P2, od1, aB3); aC3 = dot2(P3, od2, aC3);
        }
    }

    float a0 = aA0 + aB0 + aC0;
    float a1 = aA1 + aB1 + aC1;
    float a2 = aA2 + aB2 + aC2;
    float a3 = aA3 + aB3 + aC3;

    // ---- border correction (edge tiles only): F read straight from ws ----
    const int gy  = gy0 + ly;
    const int gxb = gx0 + lx0;
    if (gy < 2 || gy > 253 || gxb < 2 || gxb > 250) {
        #pragma unroll
        for (int i = 0; i < 4; ++i) {
            const int gx = gxb + i;
            float corr = 0.f;
            for (int uy = 0; uy < 3; ++uy) {
                const int qy = gy + uy - 1;
                for (int ux = 0; ux < 3; ++ux) {
                    const int qx = gx + ux - 1;
                    if ((unsigned)qy < (unsigned)IMG && (unsigned)qx < (unsigned)IMG)
                        continue;
                    for (int p = 0; p < 9; ++p) {
                        const int ry = ly + uy + (p / 3);
                        const int rx = lx0 + i + ux + (p % 3);
                        const float* fp = &ws[((uy * 3 + ux) * 9 + p) * 9];
                        for (int jj = 0; jj < 9; ++jj)
                            corr += fp[jj] * (float)s_phi[jj][ry][rx];
                    }
                }
            }
            if (i == 0) a0 -= corr;
            else if (i == 1) a1 -= corr;
            else if (i == 2) a2 -= corr;
            else a3 -= corr;
        }
    }

    const float rbv = rb[0];
    float4 o4; o4.x = a0 + rbv; o4.y = a1 + rbv; o4.z = a2 + rbv; o4.w = a3 + rbv;
    *(float4*)&out[(size_t)b * (IMG * IMG) + gy * IMG + gxb] = o4;
}

extern "C" void kernel_launch(void* const* d_in, const int* in_sizes, int n_in,
                              void* d_out, int out_size, void* d_ws, size_t ws_size,
                              hipStream_t stream) {
    const float* x             = (const float*)d_in[0];
    const float* base_w        = (const float*)d_in[1];
    const float* spline_w      = (const float*)d_in[2];
    const float* spline_scaler = (const float*)d_in[3];
    const float* restore_w     = (const float*)d_in[4];
    const float* restore_b     = (const float*)d_in[5];
    float* out = (float*)d_out;
    float* ws  = (float*)d_ws;

    kkan_precompute<<<dim3(1), dim3(1024), 0, stream>>>(
        base_w, spline_w, spline_scaler, restore_w, ws);

    dim3 grid(IMG / TS, IMG / TS, 32);
    kkan_main<<<grid, dim3(256), 0, stream>>>(x, ws, restore_b, out);
}